// Round 9
// baseline (392.498 us; speedup 1.0000x reference)
//
#include <hip/hip_runtime.h>
#include <hip/hip_fp16.h>
#include <math.h>

constexpr int N_VN   = 8000;
constexpr int N_CN   = 4000;
constexpr int DV     = 3;
constexpr int DC     = 6;
constexpr int EDGES  = N_VN * DV;   // 24000
constexpr int BATCH  = 1250;
constexpr int NUM_ITER = 5;
constexpr int NBLK   = 250;         // persistent: 5 elems/block = 2 pairs + 1 single
constexpr float LLR_MAX = 20.0f;
// 2*atanh(clip) with clip = f32(1-1e-7) = 1 - 2^-23: log((2-2^-23)/2^-23)
constexpr float MSGMAX = 16.635532f;
constexpr float FFLOOR = 2e-12f;    // floor on (1-ex): reproduces ref's |t|>=1e-12
constexpr float QSCALE = 32767.0f / 20.0f;
constexpr float QINV   = 20.0f / 32767.0f;
constexpr float LOG2E  = 1.44269504f;
constexpr float LN2    = 0.69314718f;
constexpr float C3     = QSCALE * LN2;      // encode: q = log2(r)*C3
constexpr float QMSGMAX = MSGMAX * QSCALE;  // clamp in quant domain

constexpr int MTPB  = 1024;                 // 16 waves; 96KB LDS -> 1 block/CU
constexpr int VREM  = N_VN - 7 * MTPB;      // 832  (VN round r==7 guard)
constexpr int CREM  = N_CN - 3 * MTPB;      // 928  (CN round k==3 guard)

// pair codec: signed f16 ex = copysign(exp(-|mw|), mw), 2 elems per dword
__device__ __forceinline__ unsigned pack_sex2(float mv0, float mv1, float w) {
    float mw0 = fminf(fmaxf(mv0 * w, -LLR_MAX), LLR_MAX);
    float mw1 = fminf(fmaxf(mv1 * w, -LLR_MAX), LLR_MAX);
    float e0 = exp2f(-fabsf(mw0) * LOG2E);
    float e1 = exp2f(-fabsf(mw1) * LOG2E);
    float s0 = __uint_as_float(__float_as_uint(e0) | (__float_as_uint(mw0) & 0x80000000u));
    float s1 = __uint_as_float(__float_as_uint(e1) | (__float_as_uint(mw1) & 0x80000000u));
    auto hp = __builtin_amdgcn_cvt_pkrtz(s0, s1);   // __fp16 ext_vector(2)
    unsigned u;
    __builtin_memcpy(&u, &hp, 4);
    return u;
}

__device__ __forceinline__ float half_bits_to_f32(unsigned short hbits) {
    return __half2float(__ushort_as_half(hbits));
}

// single codec: f32 signed-ex (cheapest instruction count; R2-validated)
__device__ __forceinline__ float pack_ex(float mv, float w) {
    float mw = fminf(fmaxf(mv * w, -LLR_MAX), LLR_MAX);
    float ex = exp2f(-fabsf(mw) * LOG2E);
    return __uint_as_float(__float_as_uint(ex) | (__float_as_uint(mw) & 0x80000000u));
}

// ------------------------------------------------------------- the mega kernel
// Persistent: 250 blocks x 5 batch elems (2 pairs + 1 single).  Graph tables
// rebuilt per block via LDS atomics (slot order arbitrary: product commutes),
// amortized over the 5 elements.  All 5-iteration BP state in 96 KB LDS,
// column-major (word = c + slot*4000; 4000%32==0 -> CN phase conflict-free).
// __launch_bounds__(1024, 4): a 16-wave block is 4 waves/SIMD -> VGPR cap 128.
// (R8's default cap of 64 spilled the persistent tables: ~90 MB/dispatch of
// scratch writes.  R3/R4's MISTAKE was clauses that LOWERED the cap below
// need; this one raises it to exactly the resident configuration.)
__global__ __launch_bounds__(MTPB, 4) void bp_mega_k(const float* __restrict__ noise,
                                                     const float* __restrict__ weights,
                                                     const int* __restrict__ cn_idx,
                                                     const int* __restrict__ ebno,
                                                     float* __restrict__ llr_out,
                                                     float* __restrict__ chat_out,
                                                     float* __restrict__ c_out,
                                                     float* __restrict__ loss_part) {
    __shared__ unsigned eSu[EDGES];        // 96000 B edge state (pair/single)
    __shared__ float hs[2];
    __shared__ float red[MTPB / 64];

    const int tid  = threadIdx.x;
    const int base = blockIdx.x * 5;

    if (tid == 0) {
        double sig2 = 2.0 * pow(10.0, (double)ebno[0] * 0.1);  // 4/no
        hs[0] = (float)(sig2 * 0.5);
        hs[1] = (float)sqrt(sig2);
    }

    // ---- in-block graph build (overlay on eSu): cnt[4000] ints + epos[24000] u16
    int*            cnt   = (int*)eSu;                   // eSu[0..3999]
    unsigned short* eposS = (unsigned short*)(eSu + 4000); // eSu[4000..15999]
    #pragma unroll
    for (int k = 0; k < 4; ++k) {
        int i = tid + k * MTPB;
        if (k < 3 || tid < CREM) cnt[i] = 0;
    }
    __syncthreads();
    for (int e = tid; e < EDGES; e += MTPB) {
        int c = cn_idx[e];
        int slot = atomicAdd(&cnt[c], 1);
        eposS[e] = (unsigned short)(slot * N_CN + c);    // column-major word idx
    }
    __syncthreads();
    // ---- persistent per-thread tables (shared by all 5 elements)
    int   pp[8][DV];
    float wt[8][DV];
    #pragma unroll
    for (int r = 0; r < 8; ++r) {
        int v = tid + r * MTPB;
        if (r < 7 || tid < VREM) {
            #pragma unroll
            for (int l = 0; l < DV; ++l) {
                pp[r][l] = eposS[v + l * N_VN];
                wt[r][l] = weights[v + l * N_VN];
            }
        }
    }
    const float h = hs[0], s = hs[1];

    float spMax = 0.0f, spLog = 0.0f;

    // ================= pair path (f16-ex / int16-q, 2 elems per dword) =======
    auto run_pair = [&](int b0i, int b1i) {
        const float* nrow0 = noise    + (size_t)b0i * N_VN;
        const float* nrow1 = noise    + (size_t)b1i * N_VN;
        float*       lrow0 = llr_out  + (size_t)b0i * N_VN;
        float*       lrow1 = llr_out  + (size_t)b1i * N_VN;
        float*       crow0 = chat_out + (size_t)b0i * N_VN;
        float*       crow1 = chat_out + (size_t)b1i * N_VN;
        float*       zrow0 = c_out    + (size_t)b0i * N_VN;
        float*       zrow1 = c_out    + (size_t)b1i * N_VN;
        float L0[8], L1[8];
        __syncthreads();                     // protect prior reads of eSu
        #pragma unroll
        for (int r = 0; r < 8; ++r) {
            int v = tid + r * MTPB;
            if (r < 7 || tid < VREM) {
                float n0 = nrow0[v], n1 = nrow1[v];
                float llr0 = fmaf(s, n0, -h), llr1 = fmaf(s, n1, -h);
                lrow0[v] = llr0; lrow1[v] = llr1;
                zrow0[v] = 0.0f; zrow1[v] = 0.0f;
                L0[r] = -llr0; L1[r] = -llr1;         // L = -llr
                #pragma unroll
                for (int l = 0; l < DV; ++l)
                    eSu[pp[r][l]] = pack_sex2(L0[r], L1[r], wt[r][l]);
            }
        }
        #pragma unroll 1
        for (int it = 0; it < NUM_ITER; ++it) {
            __syncthreads();                 // edge buf holds f16-ex pairs
            #pragma unroll
            for (int k = 0; k < 4; ++k) {
                int c = tid + k * MTPB;
                if (k < 3 || tid < CREM) {
                    unsigned d[DC];
                    float f0[DC], f1[DC];
                    // ILP: two independent sub-product chains per element
                    float na0 = 1.0f, nb0 = 1.0f, da0 = 1.0f, db0 = 1.0f;
                    float na1 = 1.0f, nb1 = 1.0f, da1 = 1.0f, db1 = 1.0f;
                    unsigned sx = 0u;
                    #pragma unroll
                    for (int j = 0; j < DC; ++j) {
                        d[j] = eSu[c + j * N_CN];
                        sx ^= d[j];
                        float s0 = half_bits_to_f32((unsigned short)d[j]);
                        float s1 = half_bits_to_f32((unsigned short)(d[j] >> 16));
                        float F0 = fmaxf(1.0f - fabsf(s0), FFLOOR);
                        float F1 = fmaxf(1.0f - fabsf(s1), FFLOOR);
                        f0[j] = F0; f1[j] = F1;
                        if (j & 1) { nb0 *= F0; db0 *= (2.0f - F0);
                                     nb1 *= F1; db1 *= (2.0f - F1); }
                        else       { na0 *= F0; da0 *= (2.0f - F0);
                                     na1 *= F1; da1 *= (2.0f - F1); }
                    }
                    float T0 = __fdividef(na0 * nb0, da0 * db0);   // |prod t|
                    float T1 = __fdividef(na1 * nb1, da1 * db1);
                    #pragma unroll
                    for (int j = 0; j < DC; ++j) {
                        float g0 = T0 * (2.0f - f0[j]);
                        float g1 = T1 * (2.0f - f1[j]);
                        float r0 = __fdividef(f0[j] + g0, f0[j] - g0);
                        float r1 = __fdividef(f1[j] + g1, f1[j] - g1);
                        float q0 = fminf(__log2f(r0) * C3, QMSGMAX);
                        float q1 = fminf(__log2f(r1) * C3, QMSGMAX);
                        unsigned sp = sx ^ d[j];
                        float m0 = __uint_as_float(__float_as_uint(q0) ^ ((sp & 0x8000u) << 16));
                        float m1 = __uint_as_float(__float_as_uint(q1) ^ (sp & 0x80000000u));
                        int i0 = __float2int_rn(m0);
                        int i1 = __float2int_rn(m1);
                        eSu[c + j * N_CN] = ((unsigned)i0 & 0xffffu) | ((unsigned)i1 << 16);
                    }
                }
            }
            __syncthreads();                 // edge buf holds int16-q pairs
            const bool wr = (it != NUM_ITER - 1);
            #pragma unroll
            for (int r = 0; r < 8; ++r) {
                int v = tid + r * MTPB;
                if (r < 7 || tid < VREM) {
                    unsigned da = eSu[pp[r][0]];
                    unsigned db = eSu[pp[r][1]];
                    unsigned dc = eSu[pp[r][2]];
                    int a0 = (int)(short)da, a1 = (int)da >> 16;
                    int b0 = (int)(short)db, b1 = (int)db >> 16;
                    int c0 = (int)(short)dc, c1 = (int)dc >> 16;
                    float xt0 = fmaf((float)(a0 + b0 + c0), QINV, L0[r]);
                    float xt1 = fmaf((float)(a1 + b1 + c1), QINV, L1[r]);
                    if (wr) {
                        float ma0 = fmaf((float)a0, -QINV, xt0);
                        float ma1 = fmaf((float)a1, -QINV, xt1);
                        float mb0 = fmaf((float)b0, -QINV, xt0);
                        float mb1 = fmaf((float)b1, -QINV, xt1);
                        float mc0 = fmaf((float)c0, -QINV, xt0);
                        float mc1 = fmaf((float)c1, -QINV, xt1);
                        eSu[pp[r][0]] = pack_sex2(ma0, ma1, wt[r][0]);
                        eSu[pp[r][1]] = pack_sex2(mb0, mb1, wt[r][1]);
                        eSu[pp[r][2]] = pack_sex2(mc0, mc1, wt[r][2]);
                    } else {
                        crow0[v] = -xt0;
                        crow1[v] = -xt1;
                    }
                    spMax += fmaxf(-xt0, 0.0f) + fmaxf(-xt1, 0.0f);
                    spLog += __log2f(1.0f + exp2f(-fabsf(xt0) * LOG2E));
                    spLog += __log2f(1.0f + exp2f(-fabsf(xt1) * LOG2E));
                }
            }
        }
    };

    // ================= single path (f32 signed-ex, cheapest insts) ===========
    auto run_single = [&](int b0i) {
        float* eSf = (float*)eSu;
        const float* nrow = noise    + (size_t)b0i * N_VN;
        float*       lrow = llr_out  + (size_t)b0i * N_VN;
        float*       crow = chat_out + (size_t)b0i * N_VN;
        float*       zrow = c_out    + (size_t)b0i * N_VN;
        float Lr[8];
        __syncthreads();                     // protect prior reads of eSu
        #pragma unroll
        for (int r = 0; r < 8; ++r) {
            int v = tid + r * MTPB;
            if (r < 7 || tid < VREM) {
                float nv  = nrow[v];
                float llr = fmaf(s, nv, -h);
                lrow[v] = llr;
                zrow[v] = 0.0f;
                Lr[r] = -llr;
                #pragma unroll
                for (int l = 0; l < DV; ++l)
                    eSf[pp[r][l]] = pack_ex(Lr[r], wt[r][l]);
            }
        }
        #pragma unroll 1
        for (int it = 0; it < NUM_ITER; ++it) {
            __syncthreads();                 // edge buf holds f32 signed-ex
            #pragma unroll
            for (int k = 0; k < 4; ++k) {
                int c = tid + k * MTPB;
                if (k < 3 || tid < CREM) {
                    float se[DC], f[DC];
                    float na = 1.0f, nb = 1.0f, da = 1.0f, db = 1.0f;
                    unsigned sx = 0u;
                    #pragma unroll
                    for (int j = 0; j < DC; ++j) {
                        se[j] = eSf[c + j * N_CN];
                        float F = fmaxf(1.0f - fabsf(se[j]), FFLOOR);
                        f[j] = F;
                        if (j & 1) { nb *= F; db *= (2.0f - F); }
                        else       { na *= F; da *= (2.0f - F); }
                        sx ^= __float_as_uint(se[j]);
                    }
                    float T = __fdividef(na * nb, da * db);
                    #pragma unroll
                    for (int j = 0; j < DC; ++j) {
                        float g  = T * (2.0f - f[j]);
                        float rr = __fdividef(f[j] + g, f[j] - g);
                        float ma = fminf(__log2f(rr) * LN2, MSGMAX);
                        unsigned sg = (sx ^ __float_as_uint(se[j])) & 0x80000000u;
                        eSf[c + j * N_CN] = __uint_as_float(__float_as_uint(ma) ^ sg);
                    }
                }
            }
            __syncthreads();                 // edge buf holds f32 msg_cn
            const bool wr = (it != NUM_ITER - 1);
            #pragma unroll
            for (int r = 0; r < 8; ++r) {
                int v = tid + r * MTPB;
                if (r < 7 || tid < VREM) {
                    float m0 = eSf[pp[r][0]];
                    float m1 = eSf[pp[r][1]];
                    float m2 = eSf[pp[r][2]];
                    float xt = Lr[r] + m0 + m1 + m2;
                    if (wr) {
                        eSf[pp[r][0]] = pack_ex(xt - m0, wt[r][0]);
                        eSf[pp[r][1]] = pack_ex(xt - m1, wt[r][1]);
                        eSf[pp[r][2]] = pack_ex(xt - m2, wt[r][2]);
                    } else {
                        crow[v] = -xt;
                    }
                    spMax += fmaxf(-xt, 0.0f);
                    spLog += __log2f(1.0f + exp2f(-fabsf(xt) * LOG2E));
                }
            }
        }
    };

    run_pair(base, base + 1);
    run_pair(base + 2, base + 3);
    run_single(base + 4);

    float lossacc = fmaf(LN2, spLog, spMax);

    // ---- block loss reduction -> loss_part[block]
    #pragma unroll
    for (int off = 32; off > 0; off >>= 1)
        lossacc += __shfl_down(lossacc, off, 64);
    int lane = tid & 63, wid = tid >> 6;
    if (lane == 0) red[wid] = lossacc;
    __syncthreads();
    if (tid == 0) {
        float ssum = 0.0f;
        #pragma unroll
        for (int i = 0; i < MTPB / 64; ++i) ssum += red[i];
        loss_part[blockIdx.x] = ssum;
    }
}

// ---------------------------------------------------- final loss over 250 blocks
__global__ __launch_bounds__(256) void loss_final_k(const float* __restrict__ lp,
                                                    float* __restrict__ out_loss) {
    double s = 0.0;
    for (int i = threadIdx.x; i < NBLK; i += 256) s += (double)lp[i];
    #pragma unroll
    for (int off = 32; off > 0; off >>= 1)
        s += __shfl_down(s, off, 64);
    __shared__ double red[4];
    int lane = threadIdx.x & 63, wid = threadIdx.x >> 6;
    if (lane == 0) red[wid] = s;
    __syncthreads();
    if (threadIdx.x == 0)
        out_loss[0] = (float)((red[0] + red[1] + red[2] + red[3]) /
                              ((double)NUM_ITER * (double)BATCH * (double)N_VN));
}

// ---------------------------------------------------------------------- launch
extern "C" void kernel_launch(void* const* d_in, const int* in_sizes, int n_in,
                              void* d_out, int out_size, void* d_ws, size_t ws_size,
                              hipStream_t stream) {
    const float* noise   = (const float*)d_in[0];   // (1250, 8000)
    const float* weights = (const float*)d_in[1];   // (24000,)
    // d_in[2] = vn_idx (unused: vn_idx[e] == e % 8000 by construction)
    const int* cn_idx    = (const int*)d_in[3];     // (24000,)
    const int* ebno      = (const int*)d_in[4];     // scalar int

    float* out      = (float*)d_out;
    float* out_c    = out;                 // (1250,8000) zeros (written by mega)
    float* out_chat = out + 10000000;      // (1250,8000)
    float* out_llr  = out + 20000000;      // (1250,8000)
    float* out_loss = out + 30000000;      // scalar

    float* loss_part = (float*)d_ws;       // 250*4 bytes

    bp_mega_k<<<dim3(NBLK), dim3(MTPB), 0, stream>>>(noise, weights, cn_idx, ebno,
                                                     out_llr, out_chat, out_c, loss_part);

    loss_final_k<<<dim3(1), dim3(256), 0, stream>>>(loss_part, out_loss);
}

// Round 10
// 378.674 us; speedup vs baseline: 1.0365x; 1.0365x over previous
//
#include <hip/hip_runtime.h>
#include <hip/hip_fp16.h>
#include <math.h>

constexpr int N_VN   = 8000;
constexpr int N_CN   = 4000;
constexpr int DV     = 3;
constexpr int DC     = 6;
constexpr int EDGES  = N_VN * DV;   // 24000
constexpr int BATCH  = 1250;
constexpr int NUM_ITER = 5;
constexpr int NBLK   = 250;         // persistent: 5 elems/block = 2 pairs + 1 single
constexpr float LLR_MAX = 20.0f;
// 2*atanh(clip) with clip = f32(1-1e-7) = 1 - 2^-23: log((2-2^-23)/2^-23)
constexpr float MSGMAX = 16.635532f;
constexpr float FFLOOR = 2e-12f;    // floor on (1-ex): reproduces ref's |t|>=1e-12
constexpr float QSCALE = 32767.0f / 20.0f;
constexpr float QINV   = 20.0f / 32767.0f;
constexpr float LOG2E  = 1.44269504f;
constexpr float LN2    = 0.69314718f;
constexpr float C3     = QSCALE * LN2;      // encode: q = log2(r)*C3
constexpr float QMSGMAX = MSGMAX * QSCALE;  // clamp in quant domain

constexpr int MTPB  = 1024;                 // 16 waves; ~144KB LDS -> 1 block/CU
constexpr int VREM  = N_VN - 7 * MTPB;      // 832  (VN round r==7 guard)
constexpr int CREM  = N_CN - 3 * MTPB;      // 928  (CN round k==3 guard)

// pair codec: signed f16 ex = copysign(exp(-|mw|), mw), 2 elems per dword
__device__ __forceinline__ unsigned pack_sex2(float mv0, float mv1, float w) {
    float mw0 = fminf(fmaxf(mv0 * w, -LLR_MAX), LLR_MAX);
    float mw1 = fminf(fmaxf(mv1 * w, -LLR_MAX), LLR_MAX);
    float e0 = exp2f(-fabsf(mw0) * LOG2E);
    float e1 = exp2f(-fabsf(mw1) * LOG2E);
    float s0 = __uint_as_float(__float_as_uint(e0) | (__float_as_uint(mw0) & 0x80000000u));
    float s1 = __uint_as_float(__float_as_uint(e1) | (__float_as_uint(mw1) & 0x80000000u));
    auto hp = __builtin_amdgcn_cvt_pkrtz(s0, s1);   // __fp16 ext_vector(2)
    unsigned u;
    __builtin_memcpy(&u, &hp, 4);
    return u;
}

__device__ __forceinline__ float half_bits_to_f32(unsigned short hbits) {
    return __half2float(__ushort_as_half(hbits));
}

// single codec: f32 signed-ex (decode-free)
__device__ __forceinline__ float pack_ex(float mv, float w) {
    float mw = fminf(fmaxf(mv * w, -LLR_MAX), LLR_MAX);
    float ex = exp2f(-fabsf(mw) * LOG2E);
    return __uint_as_float(__float_as_uint(ex) | (__float_as_uint(mw) & 0x80000000u));
}

// ------------------------------------------------------------- the mega kernel
// Persistent: 250 blocks x 5 batch elems (2 pairs + 1 single).
// LDS: 96 KB edge state (column-major: word = c + slot*4000, 4000%32==0 ->
// CN phase conflict-free) + 48 KB permanent u16 position table (epos).
// REGISTER-PRESSURE CONTRACT (R8/R9 lesson: compiler pins 1024-thr blocks at
// 64 VGPR and SPILLS ~88MB/dispatch if exceeded):
//   - positions live in LDS, not regs (saves 24)
//   - CN phase is two-pass (no d[]/f[] arrays; pass 2 re-reads LDS, saves ~18)
//   - persistent regs: wt[8][3] + L0/L1[8] + loss accums ~= 42; peak < 64.
__global__ __launch_bounds__(MTPB) void bp_mega_k(const float* __restrict__ noise,
                                                  const float* __restrict__ weights,
                                                  const int* __restrict__ cn_idx,
                                                  const int* __restrict__ ebno,
                                                  float* __restrict__ llr_out,
                                                  float* __restrict__ chat_out,
                                                  float* __restrict__ c_out,
                                                  float* __restrict__ loss_part) {
    __shared__ unsigned       eSu[EDGES];    // 96000 B edge state (pair/single)
    __shared__ unsigned short eposL[EDGES];  // 48000 B permanent position table
    __shared__ float hs[2];
    __shared__ float red[MTPB / 64];

    const int tid  = threadIdx.x;
    const int base = blockIdx.x * 5;

    if (tid == 0) {
        double sig2 = 2.0 * pow(10.0, (double)ebno[0] * 0.1);  // 4/no
        hs[0] = (float)(sig2 * 0.5);
        hs[1] = (float)sqrt(sig2);
    }

    // ---- in-block graph build: cnt overlays eSu; epos -> permanent LDS
    int* cnt = (int*)eSu;                    // eSu[0..3999]
    #pragma unroll
    for (int k = 0; k < 4; ++k) {
        int i = tid + k * MTPB;
        if (k < 3 || tid < CREM) cnt[i] = 0;
    }
    __syncthreads();
    for (int e = tid; e < EDGES; e += MTPB) {
        int c = cn_idx[e];
        int slot = atomicAdd(&cnt[c], 1);
        eposL[e] = (unsigned short)(slot * N_CN + c);  // column-major word idx
    }
    // ---- persistent per-thread weights (shared by all 5 elements)
    float wt[8][DV];
    #pragma unroll
    for (int r = 0; r < 8; ++r) {
        int v = tid + r * MTPB;
        if (r < 7 || tid < VREM) {
            #pragma unroll
            for (int l = 0; l < DV; ++l)
                wt[r][l] = weights[v + l * N_VN];
        }
    }
    __syncthreads();
    const float h = hs[0], s = hs[1];

    float spMax = 0.0f, spLog = 0.0f;

    // ================= pair path (f16-ex / int16-q, 2 elems per dword) =======
    auto run_pair = [&](int b0i, int b1i) {
        const float* nrow0 = noise    + (size_t)b0i * N_VN;
        const float* nrow1 = noise    + (size_t)b1i * N_VN;
        float*       lrow0 = llr_out  + (size_t)b0i * N_VN;
        float*       lrow1 = llr_out  + (size_t)b1i * N_VN;
        float*       crow0 = chat_out + (size_t)b0i * N_VN;
        float*       crow1 = chat_out + (size_t)b1i * N_VN;
        float*       zrow0 = c_out    + (size_t)b0i * N_VN;
        float*       zrow1 = c_out    + (size_t)b1i * N_VN;
        float L0[8], L1[8];
        __syncthreads();                     // protect prior element's eSu reads
        #pragma unroll
        for (int r = 0; r < 8; ++r) {
            int v = tid + r * MTPB;
            if (r < 7 || tid < VREM) {
                float n0 = nrow0[v], n1 = nrow1[v];
                float llr0 = fmaf(s, n0, -h), llr1 = fmaf(s, n1, -h);
                lrow0[v] = llr0; lrow1[v] = llr1;
                zrow0[v] = 0.0f; zrow1[v] = 0.0f;
                L0[r] = -llr0; L1[r] = -llr1;         // L = -llr
                #pragma unroll
                for (int l = 0; l < DV; ++l)
                    eSu[eposL[v + l * N_VN]] = pack_sex2(L0[r], L1[r], wt[r][l]);
            }
        }
        #pragma unroll 1
        for (int it = 0; it < NUM_ITER; ++it) {
            __syncthreads();                 // edge buf holds f16-ex pairs
            #pragma unroll 1
            for (int k = 0; k < 4; ++k) {
                int c = tid + k * MTPB;
                if (k < 3 || tid < CREM) {
                    // pass 1: products + sign parity only (minimal live set)
                    float na0 = 1.0f, nb0 = 1.0f, da0 = 1.0f, db0 = 1.0f;
                    float na1 = 1.0f, nb1 = 1.0f, da1 = 1.0f, db1 = 1.0f;
                    unsigned sx = 0u;
                    #pragma unroll
                    for (int j = 0; j < DC; ++j) {
                        unsigned d = eSu[c + j * N_CN];
                        sx ^= d;
                        float F0 = fmaxf(1.0f - fabsf(half_bits_to_f32((unsigned short)d)), FFLOOR);
                        float F1 = fmaxf(1.0f - fabsf(half_bits_to_f32((unsigned short)(d >> 16))), FFLOOR);
                        if (j & 1) { nb0 *= F0; db0 *= (2.0f - F0);
                                     nb1 *= F1; db1 *= (2.0f - F1); }
                        else       { na0 *= F0; da0 *= (2.0f - F0);
                                     na1 *= F1; da1 *= (2.0f - F1); }
                    }
                    float T0 = __fdividef(na0 * nb0, da0 * db0);   // |prod t|
                    float T1 = __fdividef(na1 * nb1, da1 * db1);
                    // pass 2: re-read each edge, recompute F, encode in-place
                    #pragma unroll
                    for (int j = 0; j < DC; ++j) {
                        unsigned d = eSu[c + j * N_CN];
                        float F0 = fmaxf(1.0f - fabsf(half_bits_to_f32((unsigned short)d)), FFLOOR);
                        float F1 = fmaxf(1.0f - fabsf(half_bits_to_f32((unsigned short)(d >> 16))), FFLOOR);
                        float g0 = T0 * (2.0f - F0);
                        float g1 = T1 * (2.0f - F1);
                        float r0 = __fdividef(F0 + g0, F0 - g0);
                        float r1 = __fdividef(F1 + g1, F1 - g1);
                        float q0 = fminf(__log2f(r0) * C3, QMSGMAX);  // NaN/inf->clamp
                        float q1 = fminf(__log2f(r1) * C3, QMSGMAX);
                        unsigned sp = sx ^ d;
                        float m0 = __uint_as_float(__float_as_uint(q0) ^ ((sp & 0x8000u) << 16));
                        float m1 = __uint_as_float(__float_as_uint(q1) ^ (sp & 0x80000000u));
                        int i0 = __float2int_rn(m0);
                        int i1 = __float2int_rn(m1);
                        eSu[c + j * N_CN] = ((unsigned)i0 & 0xffffu) | ((unsigned)i1 << 16);
                    }
                }
            }
            __syncthreads();                 // edge buf holds int16-q pairs
            const bool wr = (it != NUM_ITER - 1);
            #pragma unroll 1
            for (int r = 0; r < 8; ++r) {
                int v = tid + r * MTPB;
                if (r < 7 || tid < VREM) {
                    int p0 = eposL[v];
                    int p1 = eposL[v + N_VN];
                    int p2 = eposL[v + 2 * N_VN];
                    unsigned da = eSu[p0];
                    unsigned db = eSu[p1];
                    unsigned dc = eSu[p2];
                    int a0 = (int)(short)da, a1 = (int)da >> 16;
                    int b0 = (int)(short)db, b1 = (int)db >> 16;
                    int c0 = (int)(short)dc, c1 = (int)dc >> 16;
                    float xt0 = fmaf((float)(a0 + b0 + c0), QINV, L0[r]);
                    float xt1 = fmaf((float)(a1 + b1 + c1), QINV, L1[r]);
                    if (wr) {
                        float ma0 = fmaf((float)a0, -QINV, xt0);   // xt - msg
                        float ma1 = fmaf((float)a1, -QINV, xt1);
                        float mb0 = fmaf((float)b0, -QINV, xt0);
                        float mb1 = fmaf((float)b1, -QINV, xt1);
                        float mc0 = fmaf((float)c0, -QINV, xt0);
                        float mc1 = fmaf((float)c1, -QINV, xt1);
                        eSu[p0] = pack_sex2(ma0, ma1, wt[r][0]);
                        eSu[p1] = pack_sex2(mb0, mb1, wt[r][1]);
                        eSu[p2] = pack_sex2(mc0, mc1, wt[r][2]);
                    } else {
                        crow0[v] = -xt0;
                        crow1[v] = -xt1;
                    }
                    spMax += fmaxf(-xt0, 0.0f) + fmaxf(-xt1, 0.0f);
                    spLog += __log2f(1.0f + exp2f(-fabsf(xt0) * LOG2E));
                    spLog += __log2f(1.0f + exp2f(-fabsf(xt1) * LOG2E));
                }
            }
        }
    };

    // ================= single path (f32 signed-ex, decode-free) ==============
    auto run_single = [&](int b0i) {
        float* eSf = (float*)eSu;
        const float* nrow = noise    + (size_t)b0i * N_VN;
        float*       lrow = llr_out  + (size_t)b0i * N_VN;
        float*       crow = chat_out + (size_t)b0i * N_VN;
        float*       zrow = c_out    + (size_t)b0i * N_VN;
        float Lr[8];
        __syncthreads();                     // protect prior element's eSu reads
        #pragma unroll
        for (int r = 0; r < 8; ++r) {
            int v = tid + r * MTPB;
            if (r < 7 || tid < VREM) {
                float nv  = nrow[v];
                float llr = fmaf(s, nv, -h);
                lrow[v] = llr;
                zrow[v] = 0.0f;
                Lr[r] = -llr;
                #pragma unroll
                for (int l = 0; l < DV; ++l)
                    eSf[eposL[v + l * N_VN]] = pack_ex(Lr[r], wt[r][l]);
            }
        }
        #pragma unroll 1
        for (int it = 0; it < NUM_ITER; ++it) {
            __syncthreads();                 // edge buf holds f32 signed-ex
            #pragma unroll 1
            for (int k = 0; k < 4; ++k) {
                int c = tid + k * MTPB;
                if (k < 3 || tid < CREM) {
                    float na = 1.0f, nb = 1.0f, da = 1.0f, db = 1.0f;
                    unsigned sx = 0u;
                    #pragma unroll
                    for (int j = 0; j < DC; ++j) {
                        float se = eSf[c + j * N_CN];
                        float F = fmaxf(1.0f - fabsf(se), FFLOOR);
                        if (j & 1) { nb *= F; db *= (2.0f - F); }
                        else       { na *= F; da *= (2.0f - F); }
                        sx ^= __float_as_uint(se);
                    }
                    float T = __fdividef(na * nb, da * db);
                    #pragma unroll
                    for (int j = 0; j < DC; ++j) {
                        float se = eSf[c + j * N_CN];
                        float F = fmaxf(1.0f - fabsf(se), FFLOOR);
                        float g  = T * (2.0f - F);
                        float rr = __fdividef(F + g, F - g);
                        float ma = fminf(__log2f(rr) * LN2, MSGMAX);
                        unsigned sg = (sx ^ __float_as_uint(se)) & 0x80000000u;
                        eSf[c + j * N_CN] = __uint_as_float(__float_as_uint(ma) ^ sg);
                    }
                }
            }
            __syncthreads();                 // edge buf holds f32 msg_cn
            const bool wr = (it != NUM_ITER - 1);
            #pragma unroll 1
            for (int r = 0; r < 8; ++r) {
                int v = tid + r * MTPB;
                if (r < 7 || tid < VREM) {
                    int p0 = eposL[v];
                    int p1 = eposL[v + N_VN];
                    int p2 = eposL[v + 2 * N_VN];
                    float m0 = eSf[p0];
                    float m1 = eSf[p1];
                    float m2 = eSf[p2];
                    float xt = Lr[r] + m0 + m1 + m2;
                    if (wr) {
                        eSf[p0] = pack_ex(xt - m0, wt[r][0]);
                        eSf[p1] = pack_ex(xt - m1, wt[r][1]);
                        eSf[p2] = pack_ex(xt - m2, wt[r][2]);
                    } else {
                        crow[v] = -xt;
                    }
                    spMax += fmaxf(-xt, 0.0f);
                    spLog += __log2f(1.0f + exp2f(-fabsf(xt) * LOG2E));
                }
            }
        }
    };

    run_pair(base, base + 1);
    run_pair(base + 2, base + 3);
    run_single(base + 4);

    float lossacc = fmaf(LN2, spLog, spMax);

    // ---- block loss reduction -> loss_part[block]
    #pragma unroll
    for (int off = 32; off > 0; off >>= 1)
        lossacc += __shfl_down(lossacc, off, 64);
    int lane = tid & 63, wid = tid >> 6;
    if (lane == 0) red[wid] = lossacc;
    __syncthreads();
    if (tid == 0) {
        float ssum = 0.0f;
        #pragma unroll
        for (int i = 0; i < MTPB / 64; ++i) ssum += red[i];
        loss_part[blockIdx.x] = ssum;
    }
}

// ---------------------------------------------------- final loss over 250 blocks
__global__ __launch_bounds__(256) void loss_final_k(const float* __restrict__ lp,
                                                    float* __restrict__ out_loss) {
    double s = 0.0;
    for (int i = threadIdx.x; i < NBLK; i += 256) s += (double)lp[i];
    #pragma unroll
    for (int off = 32; off > 0; off >>= 1)
        s += __shfl_down(s, off, 64);
    __shared__ double red[4];
    int lane = threadIdx.x & 63, wid = threadIdx.x >> 6;
    if (lane == 0) red[wid] = s;
    __syncthreads();
    if (threadIdx.x == 0)
        out_loss[0] = (float)((red[0] + red[1] + red[2] + red[3]) /
                              ((double)NUM_ITER * (double)BATCH * (double)N_VN));
}

// ---------------------------------------------------------------------- launch
extern "C" void kernel_launch(void* const* d_in, const int* in_sizes, int n_in,
                              void* d_out, int out_size, void* d_ws, size_t ws_size,
                              hipStream_t stream) {
    const float* noise   = (const float*)d_in[0];   // (1250, 8000)
    const float* weights = (const float*)d_in[1];   // (24000,)
    // d_in[2] = vn_idx (unused: vn_idx[e] == e % 8000 by construction)
    const int* cn_idx    = (const int*)d_in[3];     // (24000,)
    const int* ebno      = (const int*)d_in[4];     // scalar int

    float* out      = (float*)d_out;
    float* out_c    = out;                 // (1250,8000) zeros (written by mega)
    float* out_chat = out + 10000000;      // (1250,8000)
    float* out_llr  = out + 20000000;      // (1250,8000)
    float* out_loss = out + 30000000;      // scalar

    float* loss_part = (float*)d_ws;       // 250*4 bytes

    bp_mega_k<<<dim3(NBLK), dim3(MTPB), 0, stream>>>(noise, weights, cn_idx, ebno,
                                                     out_llr, out_chat, out_c, loss_part);

    loss_final_k<<<dim3(1), dim3(256), 0, stream>>>(loss_part, out_loss);
}

// Round 12
// 374.194 us; speedup vs baseline: 1.0489x; 1.0120x over previous
//
#include <hip/hip_runtime.h>
#include <hip/hip_fp16.h>
#include <math.h>

constexpr int N_VN   = 8000;
constexpr int N_CN   = 4000;
constexpr int DV     = 3;
constexpr int DC     = 6;
constexpr int EDGES  = N_VN * DV;   // 24000
constexpr int BATCH  = 1250;
constexpr int NUM_ITER = 5;
constexpr int NBLK   = 250;         // persistent: 5 elems/block = 2 pairs + 1 single
constexpr float LLR_MAX = 20.0f;
// 2*atanh(clip) with clip = f32(1-1e-7) = 1 - 2^-23: log((2-2^-23)/2^-23)
constexpr float MSGMAX = 16.635532f;
constexpr float QSCALE = 32767.0f / 20.0f;
constexpr float QINV   = 20.0f / 32767.0f;
constexpr float LOG2E  = 1.44269504f;
constexpr float LN2    = 0.69314718f;
constexpr float C3     = QSCALE * LN2;      // encode: q = log2(r)*C3
constexpr float QMSGMAX = MSGMAX * QSCALE;  // clamp in quant domain
// encode-time ceil on ex = exp(-|mw|):  ex <= 1-2^-11 (pair/f16: largest f16
// below 1; RTZ guarantees this for any f32 ex<1, clamp only catches ex==1.0)
// and ex <= 1-2^-23 (single/f32).  The implied floor on (1-ex) cancels exactly
// in the self-message (r = (1+P)/(1-P) algebraically) and perturbs other-edge
// messages by <= ~1e-7 vs the ref's EPS=1e-12 floor.  R11 ERRATum: do NOT
// store F=1-ex in f16 (absolute step near 1 destroys log-domain precision);
// ex storage keeps relative precision exactly where the atanh pole needs it.
constexpr float EXMAX16 = 0.99951171875f;   // 1 - 2^-11
constexpr float EXMAX32 = 0.99999988f;      // 1 - 2^-23

constexpr int MTPB  = 1024;                 // 16 waves; ~144KB LDS -> 1 block/CU
constexpr int VREM  = N_VN - 7 * MTPB;      // 832  (VN round r==7 guard)
constexpr int CREM  = N_CN - 3 * MTPB;      // 928  (CN round k==3 guard)

// pair codec: signed f16 ex = copysign(exp(-|mw|), mw), 2 elems per dword
__device__ __forceinline__ unsigned pack_sex2(float mv0, float mv1, float w) {
    float mw0 = fminf(fmaxf(mv0 * w, -LLR_MAX), LLR_MAX);
    float mw1 = fminf(fmaxf(mv1 * w, -LLR_MAX), LLR_MAX);
    float e0 = fminf(exp2f(-fabsf(mw0) * LOG2E), EXMAX16);
    float e1 = fminf(exp2f(-fabsf(mw1) * LOG2E), EXMAX16);
    float s0 = __uint_as_float(__float_as_uint(e0) | (__float_as_uint(mw0) & 0x80000000u));
    float s1 = __uint_as_float(__float_as_uint(e1) | (__float_as_uint(mw1) & 0x80000000u));
    auto hp = __builtin_amdgcn_cvt_pkrtz(s0, s1);   // __fp16 ext_vector(2)
    unsigned u;
    __builtin_memcpy(&u, &hp, 4);
    return u;
}

__device__ __forceinline__ float half_bits_to_f32(unsigned short hbits) {
    return __half2float(__ushort_as_half(hbits));
}

// single codec: f32 signed-ex, encode-clamped (decode = |.|, nothing else)
__device__ __forceinline__ float pack_ex(float mv, float w) {
    float mw = fminf(fmaxf(mv * w, -LLR_MAX), LLR_MAX);
    float ex = fminf(exp2f(-fabsf(mw) * LOG2E), EXMAX32);
    return __uint_as_float(__float_as_uint(ex) | (__float_as_uint(mw) & 0x80000000u));
}

// ------------------------------------------------------------- the mega kernel
// Persistent: 250 blocks x 5 batch elems (2 pairs + 1 single).
// LDS: 96 KB edge state (column-major: word = c + slot*4000, 4000%32==0 ->
// CN phase conflict-free) + 48 KB permanent u16 position table (epos).
// REGISTER-PRESSURE CONTRACT (R8/R9 lesson: compiler pins 1024-thr blocks at
// 64 VGPR and SPILLS ~88MB/dispatch if exceeded): positions in LDS; CN phase
// two-pass (no per-edge arrays); persistent regs wt[24]+L[16]+loss ~= 42.
// CN math (all-fma form):
//   pass1/edge: n=fma(-ex,n,n)  d=fma(ex,d,d)            (n*=1-ex, d*=1+ex)
//   per CN:     T=n/d;  A=1+T;  B=1-T
//   pass2/edge: r = fma(-ex,B,A) / fma(-ex,A,B)          (== (F+g)/(F-g))
//   msg = min(log2(r)*C, MAX); NaN/inf (saturation) falls into the clamp.
__global__ __launch_bounds__(MTPB) void bp_mega_k(const float* __restrict__ noise,
                                                  const float* __restrict__ weights,
                                                  const int* __restrict__ cn_idx,
                                                  const int* __restrict__ ebno,
                                                  float* __restrict__ llr_out,
                                                  float* __restrict__ chat_out,
                                                  float* __restrict__ c_out,
                                                  float* __restrict__ loss_part) {
    __shared__ unsigned       eSu[EDGES];    // 96000 B edge state (pair/single)
    __shared__ unsigned short eposL[EDGES];  // 48000 B permanent position table
    __shared__ float hs[2];
    __shared__ float red[MTPB / 64];

    const int tid  = threadIdx.x;
    const int base = blockIdx.x * 5;

    if (tid == 0) {
        double sig2 = 2.0 * pow(10.0, (double)ebno[0] * 0.1);  // 4/no
        hs[0] = (float)(sig2 * 0.5);
        hs[1] = (float)sqrt(sig2);
    }

    // ---- in-block graph build: cnt overlays eSu; epos -> permanent LDS
    int* cnt = (int*)eSu;                    // eSu[0..3999]
    #pragma unroll
    for (int k = 0; k < 4; ++k) {
        int i = tid + k * MTPB;
        if (k < 3 || tid < CREM) cnt[i] = 0;
    }
    __syncthreads();
    for (int e = tid; e < EDGES; e += MTPB) {
        int c = cn_idx[e];
        int slot = atomicAdd(&cnt[c], 1);
        eposL[e] = (unsigned short)(slot * N_CN + c);  // column-major word idx
    }
    // ---- persistent per-thread weights (shared by all 5 elements)
    float wt[8][DV];
    #pragma unroll
    for (int r = 0; r < 8; ++r) {
        int v = tid + r * MTPB;
        if (r < 7 || tid < VREM) {
            #pragma unroll
            for (int l = 0; l < DV; ++l)
                wt[r][l] = weights[v + l * N_VN];
        }
    }
    __syncthreads();
    const float h = hs[0], s = hs[1];

    float spMax = 0.0f, spLog = 0.0f;

    // ================= pair path (f16-ex / int16-q, 2 elems per dword) =======
    auto run_pair = [&](int b0i, int b1i) {
        const float* nrow0 = noise    + (size_t)b0i * N_VN;
        const float* nrow1 = noise    + (size_t)b1i * N_VN;
        float*       lrow0 = llr_out  + (size_t)b0i * N_VN;
        float*       lrow1 = llr_out  + (size_t)b1i * N_VN;
        float*       crow0 = chat_out + (size_t)b0i * N_VN;
        float*       crow1 = chat_out + (size_t)b1i * N_VN;
        float*       zrow0 = c_out    + (size_t)b0i * N_VN;
        float*       zrow1 = c_out    + (size_t)b1i * N_VN;
        float L0[8], L1[8];
        __syncthreads();                     // protect prior element's eSu reads
        #pragma unroll
        for (int r = 0; r < 8; ++r) {
            int v = tid + r * MTPB;
            if (r < 7 || tid < VREM) {
                float n0 = nrow0[v], n1 = nrow1[v];
                float llr0 = fmaf(s, n0, -h), llr1 = fmaf(s, n1, -h);
                lrow0[v] = llr0; lrow1[v] = llr1;
                zrow0[v] = 0.0f; zrow1[v] = 0.0f;
                L0[r] = -llr0; L1[r] = -llr1;         // L = -llr
                #pragma unroll
                for (int l = 0; l < DV; ++l)
                    eSu[eposL[v + l * N_VN]] = pack_sex2(L0[r], L1[r], wt[r][l]);
            }
        }
        #pragma unroll 1
        for (int it = 0; it < NUM_ITER; ++it) {
            __syncthreads();                 // edge buf holds f16-ex pairs
            #pragma unroll 1
            for (int k = 0; k < 4; ++k) {
                int c = tid + k * MTPB;
                if (k < 3 || tid < CREM) {
                    // pass 1: products + sign parity only (minimal live set)
                    float na0 = 1.0f, nb0 = 1.0f, da0 = 1.0f, db0 = 1.0f;
                    float na1 = 1.0f, nb1 = 1.0f, da1 = 1.0f, db1 = 1.0f;
                    unsigned sx = 0u;
                    #pragma unroll
                    for (int j = 0; j < DC; ++j) {
                        unsigned d = eSu[c + j * N_CN];
                        sx ^= d;
                        float ex0 = fabsf(half_bits_to_f32((unsigned short)d));
                        float ex1 = fabsf(half_bits_to_f32((unsigned short)(d >> 16)));
                        if (j & 1) { nb0 = fmaf(-ex0, nb0, nb0); db0 = fmaf(ex0, db0, db0);
                                     nb1 = fmaf(-ex1, nb1, nb1); db1 = fmaf(ex1, db1, db1); }
                        else       { na0 = fmaf(-ex0, na0, na0); da0 = fmaf(ex0, da0, da0);
                                     na1 = fmaf(-ex1, na1, na1); da1 = fmaf(ex1, da1, da1); }
                    }
                    float T0 = __fdividef(na0 * nb0, da0 * db0);   // |prod t|
                    float T1 = __fdividef(na1 * nb1, da1 * db1);
                    float A0 = 1.0f + T0, B0 = 1.0f - T0;
                    float A1 = 1.0f + T1, B1 = 1.0f - T1;
                    // pass 2: re-read each edge, encode msg in-place
                    #pragma unroll
                    for (int j = 0; j < DC; ++j) {
                        unsigned d = eSu[c + j * N_CN];
                        float ex0 = fabsf(half_bits_to_f32((unsigned short)d));
                        float ex1 = fabsf(half_bits_to_f32((unsigned short)(d >> 16)));
                        float r0 = __fdividef(fmaf(-ex0, B0, A0), fmaf(-ex0, A0, B0));
                        float r1 = __fdividef(fmaf(-ex1, B1, A1), fmaf(-ex1, A1, B1));
                        float q0 = fminf(__log2f(r0) * C3, QMSGMAX);  // NaN/inf->clamp
                        float q1 = fminf(__log2f(r1) * C3, QMSGMAX);
                        unsigned sp = sx ^ d;
                        float m0 = __uint_as_float(__float_as_uint(q0) ^ ((sp & 0x8000u) << 16));
                        float m1 = __uint_as_float(__float_as_uint(q1) ^ (sp & 0x80000000u));
                        int i0 = __float2int_rn(m0);
                        int i1 = __float2int_rn(m1);
                        eSu[c + j * N_CN] = ((unsigned)i0 & 0xffffu) | ((unsigned)i1 << 16);
                    }
                }
            }
            __syncthreads();                 // edge buf holds int16-q pairs
            const bool wr = (it != NUM_ITER - 1);
            #pragma unroll 1
            for (int r = 0; r < 8; ++r) {
                int v = tid + r * MTPB;
                if (r < 7 || tid < VREM) {
                    int p0 = eposL[v];
                    int p1 = eposL[v + N_VN];
                    int p2 = eposL[v + 2 * N_VN];
                    unsigned da = eSu[p0];
                    unsigned db = eSu[p1];
                    unsigned dc = eSu[p2];
                    int a0 = (int)(short)da, a1 = (int)da >> 16;
                    int b0 = (int)(short)db, b1 = (int)db >> 16;
                    int c0 = (int)(short)dc, c1 = (int)dc >> 16;
                    float xt0 = fmaf((float)(a0 + b0 + c0), QINV, L0[r]);
                    float xt1 = fmaf((float)(a1 + b1 + c1), QINV, L1[r]);
                    if (wr) {
                        float ma0 = fmaf((float)a0, -QINV, xt0);   // xt - msg
                        float ma1 = fmaf((float)a1, -QINV, xt1);
                        float mb0 = fmaf((float)b0, -QINV, xt0);
                        float mb1 = fmaf((float)b1, -QINV, xt1);
                        float mc0 = fmaf((float)c0, -QINV, xt0);
                        float mc1 = fmaf((float)c1, -QINV, xt1);
                        eSu[p0] = pack_sex2(ma0, ma1, wt[r][0]);
                        eSu[p1] = pack_sex2(mb0, mb1, wt[r][1]);
                        eSu[p2] = pack_sex2(mc0, mc1, wt[r][2]);
                    } else {
                        crow0[v] = -xt0;
                        crow1[v] = -xt1;
                    }
                    spMax += fmaxf(-xt0, 0.0f) + fmaxf(-xt1, 0.0f);
                    spLog += __log2f(1.0f + exp2f(-fabsf(xt0) * LOG2E));
                    spLog += __log2f(1.0f + exp2f(-fabsf(xt1) * LOG2E));
                }
            }
        }
    };

    // ================= single path (f32 signed-ex, decode-free) ==============
    auto run_single = [&](int b0i) {
        float* eSf = (float*)eSu;
        const float* nrow = noise    + (size_t)b0i * N_VN;
        float*       lrow = llr_out  + (size_t)b0i * N_VN;
        float*       crow = chat_out + (size_t)b0i * N_VN;
        float*       zrow = c_out    + (size_t)b0i * N_VN;
        float Lr[8];
        __syncthreads();                     // protect prior element's eSu reads
        #pragma unroll
        for (int r = 0; r < 8; ++r) {
            int v = tid + r * MTPB;
            if (r < 7 || tid < VREM) {
                float nv  = nrow[v];
                float llr = fmaf(s, nv, -h);
                lrow[v] = llr;
                zrow[v] = 0.0f;
                Lr[r] = -llr;
                #pragma unroll
                for (int l = 0; l < DV; ++l)
                    eSf[eposL[v + l * N_VN]] = pack_ex(Lr[r], wt[r][l]);
            }
        }
        #pragma unroll 1
        for (int it = 0; it < NUM_ITER; ++it) {
            __syncthreads();                 // edge buf holds f32 signed-ex
            #pragma unroll 1
            for (int k = 0; k < 4; ++k) {
                int c = tid + k * MTPB;
                if (k < 3 || tid < CREM) {
                    float na = 1.0f, nb = 1.0f, da = 1.0f, db = 1.0f;
                    unsigned sx = 0u;
                    #pragma unroll
                    for (int j = 0; j < DC; ++j) {
                        float se = eSf[c + j * N_CN];
                        float ex = fabsf(se);
                        if (j & 1) { nb = fmaf(-ex, nb, nb); db = fmaf(ex, db, db); }
                        else       { na = fmaf(-ex, na, na); da = fmaf(ex, da, da); }
                        sx ^= __float_as_uint(se);
                    }
                    float T = __fdividef(na * nb, da * db);
                    float A = 1.0f + T, B = 1.0f - T;
                    #pragma unroll
                    for (int j = 0; j < DC; ++j) {
                        float se = eSf[c + j * N_CN];
                        float ex = fabsf(se);
                        float rr = __fdividef(fmaf(-ex, B, A), fmaf(-ex, A, B));
                        float ma = fminf(__log2f(rr) * LN2, MSGMAX);
                        unsigned sg = (sx ^ __float_as_uint(se)) & 0x80000000u;
                        eSf[c + j * N_CN] = __uint_as_float(__float_as_uint(ma) ^ sg);
                    }
                }
            }
            __syncthreads();                 // edge buf holds f32 msg_cn
            const bool wr = (it != NUM_ITER - 1);
            #pragma unroll 1
            for (int r = 0; r < 8; ++r) {
                int v = tid + r * MTPB;
                if (r < 7 || tid < VREM) {
                    int p0 = eposL[v];
                    int p1 = eposL[v + N_VN];
                    int p2 = eposL[v + 2 * N_VN];
                    float m0 = eSf[p0];
                    float m1 = eSf[p1];
                    float m2 = eSf[p2];
                    float xt = Lr[r] + m0 + m1 + m2;
                    if (wr) {
                        eSf[p0] = pack_ex(xt - m0, wt[r][0]);
                        eSf[p1] = pack_ex(xt - m1, wt[r][1]);
                        eSf[p2] = pack_ex(xt - m2, wt[r][2]);
                    } else {
                        crow[v] = -xt;
                    }
                    spMax += fmaxf(-xt, 0.0f);
                    spLog += __log2f(1.0f + exp2f(-fabsf(xt) * LOG2E));
                }
            }
        }
    };

    run_pair(base, base + 1);
    run_pair(base + 2, base + 3);
    run_single(base + 4);

    float lossacc = fmaf(LN2, spLog, spMax);

    // ---- block loss reduction -> loss_part[block]
    #pragma unroll
    for (int off = 32; off > 0; off >>= 1)
        lossacc += __shfl_down(lossacc, off, 64);
    int lane = tid & 63, wid = tid >> 6;
    if (lane == 0) red[wid] = lossacc;
    __syncthreads();
    if (tid == 0) {
        float ssum = 0.0f;
        #pragma unroll
        for (int i = 0; i < MTPB / 64; ++i) ssum += red[i];
        loss_part[blockIdx.x] = ssum;
    }
}

// ---------------------------------------------------- final loss over 250 blocks
__global__ __launch_bounds__(256) void loss_final_k(const float* __restrict__ lp,
                                                    float* __restrict__ out_loss) {
    double s = 0.0;
    for (int i = threadIdx.x; i < NBLK; i += 256) s += (double)lp[i];
    #pragma unroll
    for (int off = 32; off > 0; off >>= 1)
        s += __shfl_down(s, off, 64);
    __shared__ double red[4];
    int lane = threadIdx.x & 63, wid = threadIdx.x >> 6;
    if (lane == 0) red[wid] = s;
    __syncthreads();
    if (threadIdx.x == 0)
        out_loss[0] = (float)((red[0] + red[1] + red[2] + red[3]) /
                              ((double)NUM_ITER * (double)BATCH * (double)N_VN));
}

// ---------------------------------------------------------------------- launch
extern "C" void kernel_launch(void* const* d_in, const int* in_sizes, int n_in,
                              void* d_out, int out_size, void* d_ws, size_t ws_size,
                              hipStream_t stream) {
    const float* noise   = (const float*)d_in[0];   // (1250, 8000)
    const float* weights = (const float*)d_in[1];   // (24000,)
    // d_in[2] = vn_idx (unused: vn_idx[e] == e % 8000 by construction)
    const int* cn_idx    = (const int*)d_in[3];     // (24000,)
    const int* ebno      = (const int*)d_in[4];     // scalar int

    float* out      = (float*)d_out;
    float* out_c    = out;                 // (1250,8000) zeros (written by mega)
    float* out_chat = out + 10000000;      // (1250,8000)
    float* out_llr  = out + 20000000;      // (1250,8000)
    float* out_loss = out + 30000000;      // scalar

    float* loss_part = (float*)d_ws;       // 250*4 bytes

    bp_mega_k<<<dim3(NBLK), dim3(MTPB), 0, stream>>>(noise, weights, cn_idx, ebno,
                                                     out_llr, out_chat, out_c, loss_part);

    loss_final_k<<<dim3(1), dim3(256), 0, stream>>>(loss_part, out_loss);
}